// Round 1
// baseline (413.169 us; speedup 1.0000x reference)
//
#include <hip/hip_runtime.h>
#include <math.h>

#define B_  2
#define D_  1536
#define L_  2048
#define N_  16
#define SEG (L_ / 64)   // 32 elements per lane
#define NCH (B_ * D_)   // 3072 channels

__device__ __forceinline__ float softplus_f(float v) {
    return (v > 20.0f) ? v : log1pf(__expf(v));
}

__global__ __launch_bounds__(256)
void ssm_scan_kernel(const float* __restrict__ x,
                     const float* __restrict__ delta,
                     const float* __restrict__ A,
                     const float* __restrict__ Bm,
                     const float* __restrict__ Cm,
                     const float* __restrict__ Dv,
                     const float* __restrict__ z,
                     const float* __restrict__ dbias,
                     float* __restrict__ out)
{
    const int wave = threadIdx.x >> 6;        // 0..3
    const int lane = threadIdx.x & 63;        // 0..63
    const int ch   = blockIdx.x * 4 + wave;   // 0..3071
    if (ch >= NCH) return;
    const int b = ch / D_;
    const int d = ch - b * D_;

    const float* xp = x     + (size_t)ch * L_ + lane * SEG;
    const float* dp = delta + (size_t)ch * L_ + lane * SEG;
    const float* zp = z     + (size_t)ch * L_ + lane * SEG;
    float*       op = out   + (size_t)ch * L_ + lane * SEG;
    const float* Bp = Bm + (size_t)b * (N_ * L_) + lane * SEG;
    const float* Cp = Cm + (size_t)b * (N_ * L_) + lane * SEG;

    const float bias = dbias[d];
    const float Dd   = Dv[d];

    // A pre-scaled by log2(e) so deltaA = exp2f(dt * A2)
    float A2[N_];
#pragma unroll
    for (int n = 0; n < N_; ++n) A2[n] = A[d * N_ + n] * 1.44269504f;

    // ---------------- phase 1: per-lane local scan from h=0 ----------------
    float S[N_];
#pragma unroll
    for (int n = 0; n < N_; ++n) S[n] = 0.0f;
    float dtsum = 0.0f;

#pragma unroll 2
    for (int i0 = 0; i0 < SEG; i0 += 4) {
        float4 dv4 = *(const float4*)(dp + i0);
        float4 xv4 = *(const float4*)(xp + i0);
        float dvv[4] = {dv4.x, dv4.y, dv4.z, dv4.w};
        float xvv[4] = {xv4.x, xv4.y, xv4.z, xv4.w};
        float dt[4], u[4];
#pragma unroll
        for (int j = 0; j < 4; ++j) {
            dt[j] = softplus_f(dvv[j] + bias);
            u[j]  = dt[j] * xvv[j];
            dtsum += dt[j];
        }
#pragma unroll
        for (int n = 0; n < N_; ++n) {
            float4 Bv4 = *(const float4*)(Bp + n * L_ + i0);
            float Bv[4] = {Bv4.x, Bv4.y, Bv4.z, Bv4.w};
            float s = S[n];
            const float a2 = A2[n];
#pragma unroll
            for (int j = 0; j < 4; ++j) {
                float dA = exp2f(dt[j] * a2);
                s = fmaf(dA, s, u[j] * Bv[j]);
            }
            S[n] = s;
        }
    }

    // product of all deltaA in this lane's segment = exp2(A2 * sum(dt))
    float P[N_];
#pragma unroll
    for (int n = 0; n < N_; ++n) P[n] = exp2f(A2[n] * dtsum);

    // ---------------- wave-level inclusive scan of (P,S) pairs -------------
    // operator: (a1,b1) o (a2,b2) = (a1*a2, b1*a2 + b2), earlier segment first
#pragma unroll
    for (int off = 1; off < 64; off <<= 1) {
#pragma unroll
        for (int n = 0; n < N_; ++n) {
            float Pp = __shfl_up(P[n], off, 64);
            float Sp = __shfl_up(S[n], off, 64);
            if (lane >= off) {
                S[n] = fmaf(Sp, P[n], S[n]);   // use pre-update P
                P[n] *= Pp;
            }
        }
    }

    // h entering this lane's segment = inclusive S of lane-1 (0 for lane 0)
    float h[N_];
#pragma unroll
    for (int n = 0; n < N_; ++n) {
        float hs = __shfl_up(S[n], 1, 64);
        h[n] = (lane == 0) ? 0.0f : hs;
    }

    // ---------------- phase 2: re-run recurrence, produce output -----------
#pragma unroll 2
    for (int i0 = 0; i0 < SEG; i0 += 4) {
        float4 dv4 = *(const float4*)(dp + i0);
        float4 xv4 = *(const float4*)(xp + i0);
        float4 zv4 = *(const float4*)(zp + i0);
        float dvv[4] = {dv4.x, dv4.y, dv4.z, dv4.w};
        float xvv[4] = {xv4.x, xv4.y, xv4.z, xv4.w};
        float zvv[4] = {zv4.x, zv4.y, zv4.z, zv4.w};
        float dt[4], u[4];
#pragma unroll
        for (int j = 0; j < 4; ++j) {
            dt[j] = softplus_f(dvv[j] + bias);
            u[j]  = dt[j] * xvv[j];
        }
        float y[4] = {0.0f, 0.0f, 0.0f, 0.0f};
#pragma unroll
        for (int n = 0; n < N_; ++n) {
            float4 Bv4 = *(const float4*)(Bp + n * L_ + i0);
            float4 Cv4 = *(const float4*)(Cp + n * L_ + i0);
            float Bv[4] = {Bv4.x, Bv4.y, Bv4.z, Bv4.w};
            float Cv[4] = {Cv4.x, Cv4.y, Cv4.z, Cv4.w};
            float hn = h[n];
            const float a2 = A2[n];
#pragma unroll
            for (int j = 0; j < 4; ++j) {
                float dA = exp2f(dt[j] * a2);
                hn = fmaf(dA, hn, u[j] * Bv[j]);
                y[j] = fmaf(hn, Cv[j], y[j]);
            }
            h[n] = hn;
        }
        float4 ov;
        float o[4];
#pragma unroll
        for (int j = 0; j < 4; ++j) {
            float sig = 1.0f / (1.0f + __expf(-zvv[j]));
            o[j] = (y[j] + xvv[j] * Dd) * (zvv[j] * sig);
        }
        ov.x = o[0]; ov.y = o[1]; ov.z = o[2]; ov.w = o[3];
        *(float4*)(op + i0) = ov;
    }
}

extern "C" void kernel_launch(void* const* d_in, const int* in_sizes, int n_in,
                              void* d_out, int out_size, void* d_ws, size_t ws_size,
                              hipStream_t stream) {
    const float* x     = (const float*)d_in[0];
    const float* delta = (const float*)d_in[1];
    const float* A     = (const float*)d_in[2];
    const float* Bm    = (const float*)d_in[3];
    const float* Cm    = (const float*)d_in[4];
    const float* Dv    = (const float*)d_in[5];
    const float* z     = (const float*)d_in[6];
    const float* dbias = (const float*)d_in[7];
    float* out = (float*)d_out;

    dim3 grid(NCH / 4);   // 768 blocks, 4 waves = 4 channels per block
    dim3 block(256);
    ssm_scan_kernel<<<grid, block, 0, stream>>>(x, delta, A, Bm, Cm, Dv, z, dbias, out);
}

// Round 2
// 276.470 us; speedup vs baseline: 1.4944x; 1.4944x over previous
//
#include <hip/hip_runtime.h>
#include <math.h>

#define B_  2
#define D_  1536
#define L_  2048
#define N_  16
#define LC  256               // chunk length along L
#define NCHUNK (L_ / LC)      // 8
#define NCH (B_ * D_)         // 3072 channels

__device__ __forceinline__ float softplus_f(float v) {
    return (v > 20.0f) ? v : log1pf(__expf(v));
}

// block = 256 threads = 4 waves = 4 channels (all same batch b).
// Loop over L in chunks of 256; B/C chunk staged in LDS (coalesced coop load,
// software-pipelined: next chunk's global loads issued before computing the
// current chunk). Per chunk: per-lane 4-elem local scan -> 6-step wave shfl
// scan -> carry fold -> pass 2 (recurrence + y = h.C) -> fused epilogue.
__global__ __launch_bounds__(256, 3)
void ssm_scan_kernel(const float* __restrict__ x,
                     const float* __restrict__ delta,
                     const float* __restrict__ A,
                     const float* __restrict__ Bm,
                     const float* __restrict__ Cm,
                     const float* __restrict__ Dv,
                     const float* __restrict__ z,
                     const float* __restrict__ dbias,
                     float* __restrict__ out)
{
    __shared__ float Bs[N_][LC];   // 16 KB
    __shared__ float Cs[N_][LC];   // 16 KB

    const int tid  = threadIdx.x;
    const int wave = tid >> 6;
    const int lane = tid & 63;
    const int ch   = blockIdx.x * 4 + wave;   // blocks never straddle b (1536%4==0)
    const int b    = ch / D_;
    const int d    = ch - b * D_;

    const float bias = dbias[d];
    const float Dd   = Dv[d];

    // A pre-scaled by log2(e) so deltaA = exp2f(dt * A2)
    float A2[N_];
#pragma unroll
    for (int n = 0; n < N_; ++n) A2[n] = A[d * N_ + n] * 1.4426950408889634f;

    const float* Bb = Bm + (size_t)b * (N_ * L_);
    const float* Cb = Cm + (size_t)b * (N_ * L_);
    const size_t chbase = (size_t)ch * L_;

    // coop-load coords: i = tid + k*256 -> row n=i>>6, float4-col c4=i&63
    int ld_n[4], ld_c4[4];
#pragma unroll
    for (int k = 0; k < 4; ++k) {
        int i = tid + k * 256;
        ld_n[k]  = i >> 6;
        ld_c4[k] = i & 63;
    }

    float carry[N_];
#pragma unroll
    for (int n = 0; n < N_; ++n) carry[n] = 0.0f;

    // ---- prefetch chunk 0 into registers ----
    float4 pB[4], pC[4], pX, pDel, pZ;
#pragma unroll
    for (int k = 0; k < 4; ++k) {
        pB[k] = *(const float4*)(Bb + ld_n[k] * L_ + ld_c4[k] * 4);
        pC[k] = *(const float4*)(Cb + ld_n[k] * L_ + ld_c4[k] * 4);
    }
    pX   = *(const float4*)(x     + chbase + lane * 4);
    pDel = *(const float4*)(delta + chbase + lane * 4);
    pZ   = *(const float4*)(z     + chbase + lane * 4);

    for (int c = 0; c < NCHUNK; ++c) {
        __syncthreads();   // previous chunk's LDS consumers done
#pragma unroll
        for (int k = 0; k < 4; ++k) {
            *(float4*)&Bs[ld_n[k]][ld_c4[k] * 4] = pB[k];
            *(float4*)&Cs[ld_n[k]][ld_c4[k] * 4] = pC[k];
        }
        float xv[4]  = {pX.x, pX.y, pX.z, pX.w};
        float dvv[4] = {pDel.x, pDel.y, pDel.z, pDel.w};
        float zv[4]  = {pZ.x, pZ.y, pZ.z, pZ.w};
        __syncthreads();   // LDS ready

        // ---- issue next chunk's global loads (overlap with compute) ----
        if (c + 1 < NCHUNK) {
            const int off = (c + 1) * LC;
#pragma unroll
            for (int k = 0; k < 4; ++k) {
                pB[k] = *(const float4*)(Bb + ld_n[k] * L_ + off + ld_c4[k] * 4);
                pC[k] = *(const float4*)(Cb + ld_n[k] * L_ + off + ld_c4[k] * 4);
            }
            pX   = *(const float4*)(x     + chbase + off + lane * 4);
            pDel = *(const float4*)(delta + chbase + off + lane * 4);
            pZ   = *(const float4*)(z     + chbase + off + lane * 4);
        }

        // ---- pass 1: per-lane local scan over 4 elems ----
        float dt[4], u[4];
        float dtsum = 0.0f;
#pragma unroll
        for (int j = 0; j < 4; ++j) {
            dt[j] = softplus_f(dvv[j] + bias);
            u[j]  = dt[j] * xv[j];
            dtsum += dt[j];
        }
        float S[N_], P[N_];
#pragma unroll
        for (int n = 0; n < N_; ++n) {
            float4 Bv4 = *(const float4*)&Bs[n][lane * 4];
            float Bvv[4] = {Bv4.x, Bv4.y, Bv4.z, Bv4.w};
            const float a2 = A2[n];
            float s = 0.0f;
#pragma unroll
            for (int j = 0; j < 4; ++j) {
                float dA = exp2f(dt[j] * a2);
                s = fmaf(dA, s, u[j] * Bvv[j]);
            }
            S[n] = s;
            P[n] = exp2f(a2 * dtsum);
        }

        // ---- wave-level inclusive scan of (P,S), earlier lane = earlier l ----
#pragma unroll
        for (int off = 1; off < 64; off <<= 1) {
#pragma unroll
            for (int n = 0; n < N_; ++n) {
                float Pp = __shfl_up(P[n], off, 64);
                float Sp = __shfl_up(S[n], off, 64);
                if (lane >= off) {
                    S[n] = fmaf(Sp, P[n], S[n]);   // pre-update P
                    P[n] *= Pp;
                }
            }
        }

        // ---- fold chunk carry; h entering this lane's segment ----
        float h[N_];
#pragma unroll
        for (int n = 0; n < N_; ++n) {
            float hinc = fmaf(carry[n], P[n], S[n]);  // true inclusive state
            float hup  = __shfl_up(hinc, 1, 64);
            float ncar = __shfl(hinc, 63, 64);
            h[n] = (lane == 0) ? carry[n] : hup;
            carry[n] = ncar;
        }

        // ---- pass 2: recurrence from h_in, y = sum_n h*C ----
        float y[4] = {0.0f, 0.0f, 0.0f, 0.0f};
#pragma unroll
        for (int n = 0; n < N_; ++n) {
            float4 Bv4 = *(const float4*)&Bs[n][lane * 4];
            float4 Cv4 = *(const float4*)&Cs[n][lane * 4];
            float Bvv[4] = {Bv4.x, Bv4.y, Bv4.z, Bv4.w};
            float Cvv[4] = {Cv4.x, Cv4.y, Cv4.z, Cv4.w};
            float hn = h[n];
            const float a2 = A2[n];
#pragma unroll
            for (int j = 0; j < 4; ++j) {
                float dA = exp2f(dt[j] * a2);
                hn = fmaf(dA, hn, u[j] * Bvv[j]);
                y[j] = fmaf(hn, Cvv[j], y[j]);
            }
        }

        // ---- fused epilogue: D-skip + SiLU gate, coalesced float4 store ----
        float o[4];
#pragma unroll
        for (int j = 0; j < 4; ++j) {
            float sig = 1.0f / (1.0f + __expf(-zv[j]));
            o[j] = (y[j] + xv[j] * Dd) * (zv[j] * sig);
        }
        float4 ov = {o[0], o[1], o[2], o[3]};
        *(float4*)(out + chbase + c * LC + lane * 4) = ov;
    }
}

extern "C" void kernel_launch(void* const* d_in, const int* in_sizes, int n_in,
                              void* d_out, int out_size, void* d_ws, size_t ws_size,
                              hipStream_t stream) {
    const float* x     = (const float*)d_in[0];
    const float* delta = (const float*)d_in[1];
    const float* A     = (const float*)d_in[2];
    const float* Bm    = (const float*)d_in[3];
    const float* Cm    = (const float*)d_in[4];
    const float* Dv    = (const float*)d_in[5];
    const float* z     = (const float*)d_in[6];
    const float* dbias = (const float*)d_in[7];
    float* out = (float*)d_out;

    dim3 grid(NCH / 4);   // 768 blocks, 4 waves = 4 channels per block
    dim3 block(256);
    ssm_scan_kernel<<<grid, block, 0, stream>>>(x, delta, A, Bm, Cm, Dv, z, dbias, out);
}

// Round 3
// 226.678 us; speedup vs baseline: 1.8227x; 1.2197x over previous
//
#include <hip/hip_runtime.h>
#include <math.h>

#define B_  2
#define D_  1536
#define L_  2048
#define N_  16
#define LC  256               // chunk length along L
#define NCHUNK (L_ / LC)      // 8
#define NCH (B_ * D_)         // 3072 channels
#define LOG2E 1.4426950408889634f
#define LN2   0.6931471805599453f

// force a wave-uniform float into an SGPR
__device__ __forceinline__ float rfl(float v) {
    return __uint_as_float(__builtin_amdgcn_readfirstlane(__float_as_uint(v)));
}
__device__ __forceinline__ float exp2fast(float x) { return __builtin_amdgcn_exp2f(x); }
__device__ __forceinline__ float log2fast(float x) { return __builtin_amdgcn_logf(x); }
__device__ __forceinline__ float rcpfast(float x)  { return __builtin_amdgcn_rcpf(x); }

__device__ __forceinline__ float softplus_f(float v) {
    float t = exp2fast(v * LOG2E);                 // e^v = 2^(v*log2e)
    float s = LN2 * log2fast(1.0f + t);            // ln(1+e^v)
    return (v > 20.0f) ? v : s;
}

// block = 256 threads = 4 waves = 4 channels (same batch b).
// Chunked along L (LC=256): B/C chunk in LDS (coalesced coop load, register
// software pipeline). Pass 1: per-lane 4-elem local scan, deltaA SAVED in
// registers (dAr[64]). Wave shfl scan of (P,S). Pass 2 reuses dAr (no exp
// recompute). Wave-uniform A2/carry/bias/D scalarized to SGPRs.
__global__ __launch_bounds__(256, 3)
void ssm_scan_kernel(const float* __restrict__ x,
                     const float* __restrict__ delta,
                     const float* __restrict__ A,
                     const float* __restrict__ Bm,
                     const float* __restrict__ Cm,
                     const float* __restrict__ Dv,
                     const float* __restrict__ z,
                     const float* __restrict__ dbias,
                     float* __restrict__ out)
{
    __shared__ float Bs[N_][LC];   // 16 KB
    __shared__ float Cs[N_][LC];   // 16 KB

    const int tid  = threadIdx.x;
    const int wave = tid >> 6;
    const int lane = tid & 63;
    const int ch   = blockIdx.x * 4 + wave;          // blocks never straddle b
    const int b    = __builtin_amdgcn_readfirstlane(ch / D_);
    const int d    = __builtin_amdgcn_readfirstlane(ch - b * D_);

    const float bias = rfl(dbias[d]);
    const float Dd   = rfl(Dv[d]);

    // A pre-scaled by log2(e); wave-uniform -> SGPRs
    float A2[N_];
#pragma unroll
    for (int n = 0; n < N_; ++n) A2[n] = rfl(A[d * N_ + n] * LOG2E);

    const float* Bb = Bm + (size_t)b * (N_ * L_);
    const float* Cb = Cm + (size_t)b * (N_ * L_);
    const size_t chbase = (size_t)ch * L_;

    // coop-load coords: i = tid + k*256 -> row n=i>>6, float4-col c4=i&63
    int ld_n[4], ld_c4[4];
#pragma unroll
    for (int k = 0; k < 4; ++k) {
        int i = tid + k * 256;
        ld_n[k]  = i >> 6;
        ld_c4[k] = i & 63;
    }

    float carry[N_];                                 // wave-uniform -> SGPRs
#pragma unroll
    for (int n = 0; n < N_; ++n) carry[n] = 0.0f;

    // ---- prefetch chunk 0 ----
    float4 pB[4], pC[4], pX, pDel, pZ;
#pragma unroll
    for (int k = 0; k < 4; ++k) {
        pB[k] = *(const float4*)(Bb + ld_n[k] * L_ + ld_c4[k] * 4);
        pC[k] = *(const float4*)(Cb + ld_n[k] * L_ + ld_c4[k] * 4);
    }
    pX   = *(const float4*)(x     + chbase + lane * 4);
    pDel = *(const float4*)(delta + chbase + lane * 4);
    pZ   = *(const float4*)(z     + chbase + lane * 4);

    for (int c = 0; c < NCHUNK; ++c) {
        __syncthreads();   // previous chunk's LDS consumers done
#pragma unroll
        for (int k = 0; k < 4; ++k) {
            *(float4*)&Bs[ld_n[k]][ld_c4[k] * 4] = pB[k];
            *(float4*)&Cs[ld_n[k]][ld_c4[k] * 4] = pC[k];
        }
        float xv[4]  = {pX.x, pX.y, pX.z, pX.w};
        float dvv[4] = {pDel.x, pDel.y, pDel.z, pDel.w};
        float zv[4]  = {pZ.x, pZ.y, pZ.z, pZ.w};
        __syncthreads();   // LDS ready

        // ---- issue next chunk's global loads (overlap with compute) ----
        if (c + 1 < NCHUNK) {
            const int off = (c + 1) * LC;
#pragma unroll
            for (int k = 0; k < 4; ++k) {
                pB[k] = *(const float4*)(Bb + ld_n[k] * L_ + off + ld_c4[k] * 4);
                pC[k] = *(const float4*)(Cb + ld_n[k] * L_ + off + ld_c4[k] * 4);
            }
            pX   = *(const float4*)(x     + chbase + off + lane * 4);
            pDel = *(const float4*)(delta + chbase + off + lane * 4);
            pZ   = *(const float4*)(z     + chbase + off + lane * 4);
        }

        // ---- pass 1: per-lane local scan; save deltaA in regs ----
        float dt[4], u[4];
        float dtsum = 0.0f;
#pragma unroll
        for (int j = 0; j < 4; ++j) {
            dt[j] = softplus_f(dvv[j] + bias);
            u[j]  = dt[j] * xv[j];
            dtsum += dt[j];
        }
        float S[N_], P[N_];
        float dAr[4 * N_];                       // statically indexed -> VGPRs
#pragma unroll
        for (int n = 0; n < N_; ++n) {
            float4 Bv4 = *(const float4*)&Bs[n][lane * 4];
            float Bvv[4] = {Bv4.x, Bv4.y, Bv4.z, Bv4.w};
            const float a2 = A2[n];
            float s = 0.0f;
#pragma unroll
            for (int j = 0; j < 4; ++j) {
                float e = exp2fast(dt[j] * a2);
                dAr[(n << 2) + j] = e;
                s = fmaf(e, s, u[j] * Bvv[j]);
            }
            S[n] = s;
            P[n] = exp2fast(a2 * dtsum);
        }

        // ---- wave-level inclusive scan of (P,S) ----
#pragma unroll
        for (int off = 1; off < 64; off <<= 1) {
#pragma unroll
            for (int n = 0; n < N_; ++n) {
                float Pp = __shfl_up(P[n], off, 64);
                float Sp = __shfl_up(S[n], off, 64);
                if (lane >= off) {
                    S[n] = fmaf(Sp, P[n], S[n]);   // pre-update P
                    P[n] *= Pp;
                }
            }
        }

        // ---- fold chunk carry; h entering this lane's segment ----
        float h[N_];
#pragma unroll
        for (int n = 0; n < N_; ++n) {
            float hinc = fmaf(carry[n], P[n], S[n]);  // true inclusive state
            float hup  = __shfl_up(hinc, 1, 64);
            float ncar = __shfl(hinc, 63, 64);
            h[n] = (lane == 0) ? carry[n] : hup;
            carry[n] = rfl(ncar);                     // SGPR loop-carry
        }

        // ---- pass 2: recurrence from h_in using saved dAr; y = sum_n h*C ----
        float y[4] = {0.0f, 0.0f, 0.0f, 0.0f};
#pragma unroll
        for (int n = 0; n < N_; ++n) {
            float4 Bv4 = *(const float4*)&Bs[n][lane * 4];
            float4 Cv4 = *(const float4*)&Cs[n][lane * 4];
            float Bvv[4] = {Bv4.x, Bv4.y, Bv4.z, Bv4.w};
            float Cvv[4] = {Cv4.x, Cv4.y, Cv4.z, Cv4.w};
            float hn = h[n];
#pragma unroll
            for (int j = 0; j < 4; ++j) {
                hn = fmaf(dAr[(n << 2) + j], hn, u[j] * Bvv[j]);
                y[j] = fmaf(hn, Cvv[j], y[j]);
            }
        }

        // ---- fused epilogue: D-skip + SiLU gate, coalesced float4 store ----
        float o[4];
#pragma unroll
        for (int j = 0; j < 4; ++j) {
            float sig = rcpfast(1.0f + exp2fast(-zv[j] * LOG2E));
            o[j] = (y[j] + xv[j] * Dd) * (zv[j] * sig);
        }
        float4 ov = {o[0], o[1], o[2], o[3]};
        *(float4*)(out + chbase + c * LC + lane * 4) = ov;
    }
}

extern "C" void kernel_launch(void* const* d_in, const int* in_sizes, int n_in,
                              void* d_out, int out_size, void* d_ws, size_t ws_size,
                              hipStream_t stream) {
    const float* x     = (const float*)d_in[0];
    const float* delta = (const float*)d_in[1];
    const float* A     = (const float*)d_in[2];
    const float* Bm    = (const float*)d_in[3];
    const float* Cm    = (const float*)d_in[4];
    const float* Dv    = (const float*)d_in[5];
    const float* z     = (const float*)d_in[6];
    const float* dbias = (const float*)d_in[7];
    float* out = (float*)d_out;

    dim3 grid(NCH / 4);   // 768 blocks, 4 waves = 4 channels per block
    dim3 block(256);
    ssm_scan_kernel<<<grid, block, 0, stream>>>(x, delta, A, Bm, Cm, Dv, z, dbias, out);
}

// Round 4
// 224.719 us; speedup vs baseline: 1.8386x; 1.0087x over previous
//
#include <hip/hip_runtime.h>
#include <math.h>

#define B_  2
#define D_  1536
#define L_  2048
#define N_  16
#define NH  8                 // states per half-wave
#define LC  128               // chunk length along L (32 segs x 4 elems)
#define NCHUNK (L_ / LC)      // 16
#define NCH (B_ * D_)         // 3072 channels
#define LOG2E 1.4426950408889634f
#define LN2   0.6931471805599453f

__device__ __forceinline__ float rfl(float v) {
    return __uint_as_float(__builtin_amdgcn_readfirstlane(__float_as_uint(v)));
}
__device__ __forceinline__ float exp2fast(float x) { return __builtin_amdgcn_exp2f(x); }
__device__ __forceinline__ float log2fast(float x) { return __builtin_amdgcn_logf(x); }
__device__ __forceinline__ float rcpfast(float x)  { return __builtin_amdgcn_rcpf(x); }

__device__ __forceinline__ float softplus_f(float v) {
    float t = exp2fast(v * LOG2E);                 // e^v
    float s = LN2 * log2fast(1.0f + t);            // ln(1+e^v)
    return (v > 20.0f) ? v : s;
}

// wave = 1 channel. lane = (g,s): g=lane>>5 owns 8 of the 16 states,
// s=lane&31 owns a 4-elem L-segment. Chunk LC=128 along L; B/C staged in LDS
// (coop coalesced load, register prefetch pipeline). Branchless width-32 shfl
// scan (neutral-element select -> unconditional array writes -> no scratch).
// y finished with shfl_xor(32); half-wave stores.
__global__ __launch_bounds__(256, 3)
void ssm_scan_kernel(const float* __restrict__ x,
                     const float* __restrict__ delta,
                     const float* __restrict__ A,
                     const float* __restrict__ Bm,
                     const float* __restrict__ Cm,
                     const float* __restrict__ Dv,
                     const float* __restrict__ z,
                     const float* __restrict__ dbias,
                     float* __restrict__ out)
{
    __shared__ float Bs[N_][LC];   // 8 KB
    __shared__ float Cs[N_][LC];   // 8 KB

    const int tid  = threadIdx.x;
    const int wave = tid >> 6;
    const int lane = tid & 63;
    const int s    = lane & 31;    // L-segment index within chunk
    const int g    = lane >> 5;    // state-group (n in [8g, 8g+8))
    const int ch   = blockIdx.x * 4 + wave;          // blocks never straddle b
    const int b    = __builtin_amdgcn_readfirstlane(ch / D_);
    const int d    = __builtin_amdgcn_readfirstlane(ch - b * D_);

    const float bias = rfl(dbias[d]);
    const float Dd   = rfl(Dv[d]);

    // this half-wave's 8 A values, pre-scaled by log2(e)
    float A2[NH];
#pragma unroll
    for (int i = 0; i < NH; ++i) A2[i] = A[d * N_ + NH * g + i] * LOG2E;

    const float* Bb = Bm + (size_t)b * (N_ * L_);
    const float* Cb = Cm + (size_t)b * (N_ * L_);
    const size_t chbase = (size_t)ch * L_;

    // coop-load coords: i = tid + k*256 -> row n=i>>5, float4-col c4=i&31
    int ld_n[2], ld_c4[2];
#pragma unroll
    for (int k = 0; k < 2; ++k) {
        int i = tid + k * 256;
        ld_n[k]  = i >> 5;
        ld_c4[k] = i & 31;
    }

    float carry[NH];
#pragma unroll
    for (int i = 0; i < NH; ++i) carry[i] = 0.0f;

    // ---- prefetch chunk 0 ----
    float4 pB[2], pC[2], pX, pDel, pZ;
#pragma unroll
    for (int k = 0; k < 2; ++k) {
        pB[k] = *(const float4*)(Bb + ld_n[k] * L_ + ld_c4[k] * 4);
        pC[k] = *(const float4*)(Cb + ld_n[k] * L_ + ld_c4[k] * 4);
    }
    pX   = *(const float4*)(x     + chbase + s * 4);
    pDel = *(const float4*)(delta + chbase + s * 4);
    pZ   = *(const float4*)(z     + chbase + s * 4);

    for (int c = 0; c < NCHUNK; ++c) {
        __syncthreads();   // previous chunk's LDS consumers done
#pragma unroll
        for (int k = 0; k < 2; ++k) {
            *(float4*)&Bs[ld_n[k]][ld_c4[k] * 4] = pB[k];
            *(float4*)&Cs[ld_n[k]][ld_c4[k] * 4] = pC[k];
        }
        float xv[4]  = {pX.x, pX.y, pX.z, pX.w};
        float dvv[4] = {pDel.x, pDel.y, pDel.z, pDel.w};
        float zv[4]  = {pZ.x, pZ.y, pZ.z, pZ.w};
        __syncthreads();   // LDS ready

        // ---- issue next chunk's global loads (overlap with compute) ----
        if (c + 1 < NCHUNK) {
            const int off = (c + 1) * LC;
#pragma unroll
            for (int k = 0; k < 2; ++k) {
                pB[k] = *(const float4*)(Bb + ld_n[k] * L_ + off + ld_c4[k] * 4);
                pC[k] = *(const float4*)(Cb + ld_n[k] * L_ + off + ld_c4[k] * 4);
            }
            pX   = *(const float4*)(x     + chbase + off + s * 4);
            pDel = *(const float4*)(delta + chbase + off + s * 4);
            pZ   = *(const float4*)(z     + chbase + off + s * 4);
        }

        // ---- pass 1: per-lane local scan over 4 elems x 8 states ----
        float dt[4], u[4];
        float dtsum = 0.0f;
#pragma unroll
        for (int j = 0; j < 4; ++j) {
            dt[j] = softplus_f(dvv[j] + bias);
            u[j]  = dt[j] * xv[j];
            dtsum += dt[j];
        }
        float S[NH], P[NH];
        float dAr[4 * NH];                 // statically indexed -> VGPRs
#pragma unroll
        for (int i = 0; i < NH; ++i) {
            float4 Bv4 = *(const float4*)&Bs[NH * g + i][s * 4];
            float Bvv[4] = {Bv4.x, Bv4.y, Bv4.z, Bv4.w};
            const float a2 = A2[i];
            float acc = 0.0f;
#pragma unroll
            for (int j = 0; j < 4; ++j) {
                float e = exp2fast(dt[j] * a2);
                dAr[(i << 2) + j] = e;
                acc = fmaf(e, acc, u[j] * Bvv[j]);
            }
            S[i] = acc;
            P[i] = exp2fast(a2 * dtsum);
        }

        // ---- width-32 inclusive scan of (P,S), branchless ----
#pragma unroll
        for (int off = 1; off < 32; off <<= 1) {
#pragma unroll
            for (int i = 0; i < NH; ++i) {
                float Pp = __shfl_up(P[i], off, 32);
                float Sp = __shfl_up(S[i], off, 32);
                Pp = (s >= off) ? Pp : 1.0f;       // neutral element
                Sp = (s >= off) ? Sp : 0.0f;
                S[i] = fmaf(Sp, P[i], S[i]);       // unconditional writes
                P[i] *= Pp;
            }
        }

        // ---- fold chunk carry; h entering this lane's segment ----
        float h[NH];
#pragma unroll
        for (int i = 0; i < NH; ++i) {
            float hinc = fmaf(carry[i], P[i], S[i]);  // true inclusive state
            float hup  = __shfl_up(hinc, 1, 32);
            h[i]       = (s == 0) ? carry[i] : hup;
            carry[i]   = __shfl(hinc, 31, 32);        // broadcast within group
        }

        // ---- pass 2: recurrence from h_in using saved dAr; y = sum_n h*C ----
        float y[4] = {0.0f, 0.0f, 0.0f, 0.0f};
#pragma unroll
        for (int i = 0; i < NH; ++i) {
            float4 Bv4 = *(const float4*)&Bs[NH * g + i][s * 4];
            float4 Cv4 = *(const float4*)&Cs[NH * g + i][s * 4];
            float Bvv[4] = {Bv4.x, Bv4.y, Bv4.z, Bv4.w};
            float Cvv[4] = {Cv4.x, Cv4.y, Cv4.z, Cv4.w};
            float hn = h[i];
#pragma unroll
            for (int j = 0; j < 4; ++j) {
                hn = fmaf(dAr[(i << 2) + j], hn, u[j] * Bvv[j]);
                y[j] = fmaf(hn, Cvv[j], y[j]);
            }
        }

        // ---- combine the two state-halves; epilogue; half-wave store ----
        float o[4];
#pragma unroll
        for (int j = 0; j < 4; ++j) {
            float yt = y[j] + __shfl_xor(y[j], 32, 64);
            float sig = rcpfast(1.0f + exp2fast(-zv[j] * LOG2E));
            o[j] = (yt + xv[j] * Dd) * (zv[j] * sig);
        }
        if (g == 0) {
            float4 ov = {o[0], o[1], o[2], o[3]};
            *(float4*)(out + chbase + c * LC + s * 4) = ov;
        }
    }
}

extern "C" void kernel_launch(void* const* d_in, const int* in_sizes, int n_in,
                              void* d_out, int out_size, void* d_ws, size_t ws_size,
                              hipStream_t stream) {
    const float* x     = (const float*)d_in[0];
    const float* delta = (const float*)d_in[1];
    const float* A     = (const float*)d_in[2];
    const float* Bm    = (const float*)d_in[3];
    const float* Cm    = (const float*)d_in[4];
    const float* Dv    = (const float*)d_in[5];
    const float* z     = (const float*)d_in[6];
    const float* dbias = (const float*)d_in[7];
    float* out = (float*)d_out;

    dim3 grid(NCH / 4);   // 768 blocks, 4 waves = 4 channels per block
    dim3 block(256);
    ssm_scan_kernel<<<grid, block, 0, stream>>>(x, delta, A, Bm, Cm, Dv, z, dbias, out);
}

// Round 5
// 179.748 us; speedup vs baseline: 2.2986x; 1.2502x over previous
//
#include <hip/hip_runtime.h>
#include <math.h>

#define B_  2
#define D_  1536
#define L_  2048
#define N_  16
#define NH  8                 // states per half-wave
#define LC  128               // chunk length along L (32 segs x 4 elems)
#define NCHUNK (L_ / LC)      // 16
#define NCH (B_ * D_)         // 3072 channels
#define LOG2E 1.4426950408889634f
#define LN2   0.6931471805599453f

typedef float f4 __attribute__((ext_vector_type(4)));
typedef float f8 __attribute__((ext_vector_type(8)));

__device__ __forceinline__ float exp2f_(float v) { return __builtin_amdgcn_exp2f(v); }
__device__ __forceinline__ float log2f_(float v) { return __builtin_amdgcn_logf(v); }
__device__ __forceinline__ float rcpf_(float v)  { return __builtin_amdgcn_rcpf(v); }

__device__ __forceinline__ float softplus_f(float v) {
    float t = exp2f_(v * LOG2E);                   // e^v
    float r = LN2 * log2f_(1.0f + t);              // ln(1+e^v)
    return (v > 20.0f) ? v : r;
}
__device__ __forceinline__ f8 splat8(float v) { f8 r = {v,v,v,v,v,v,v,v}; return r; }
__device__ __forceinline__ f8 exp2v8(f8 a) {
    f8 r;
    r[0]=exp2f_(a[0]); r[1]=exp2f_(a[1]); r[2]=exp2f_(a[2]); r[3]=exp2f_(a[3]);
    r[4]=exp2f_(a[4]); r[5]=exp2f_(a[5]); r[6]=exp2f_(a[6]); r[7]=exp2f_(a[7]);
    return r;
}
__device__ __forceinline__ float dot8(f8 a, f8 b) {
    float p0 = fmaf(a[0], b[0], a[1]*b[1]);
    float p1 = fmaf(a[2], b[2], a[3]*b[3]);
    float p2 = fmaf(a[4], b[4], a[5]*b[5]);
    float p3 = fmaf(a[6], b[6], a[7]*b[7]);
    return (p0 + p1) + (p2 + p3);
}

// One wave (= one 64-thread block) per channel. lane=(g,s): g=lane>>5 owns 8
// of 16 states, s=lane&31 owns a 4-elem L-segment of each 128-chunk.
// No LDS, no barriers: B/C read per-lane as float4 from global (L1/L2-hot,
// coalesced per half-wave). ALL per-lane state in ext-vector SSA values ->
// scratch impossible. Branchless width-32 shfl scan; xor(32) combine.
__global__ __launch_bounds__(64, 3)
void ssm_scan_kernel(const float* __restrict__ x,
                     const float* __restrict__ delta,
                     const float* __restrict__ A,
                     const float* __restrict__ Bm,
                     const float* __restrict__ Cm,
                     const float* __restrict__ Dv,
                     const float* __restrict__ z,
                     const float* __restrict__ dbias,
                     float* __restrict__ out)
{
    const int lane = threadIdx.x;      // 0..63
    const int s    = lane & 31;
    const int g    = lane >> 5;
    const int ch   = blockIdx.x;       // one channel per wave
    const int b    = ch / D_;
    const int d    = ch - b * D_;

    const float bias = dbias[d];       // d is uniform -> scalar loads
    const float Dd   = Dv[d];

    const float* Ab = A + d * N_ + NH * g;
    f8 A2v;
    A2v[0]=Ab[0]*LOG2E; A2v[1]=Ab[1]*LOG2E; A2v[2]=Ab[2]*LOG2E; A2v[3]=Ab[3]*LOG2E;
    A2v[4]=Ab[4]*LOG2E; A2v[5]=Ab[5]*LOG2E; A2v[6]=Ab[6]*LOG2E; A2v[7]=Ab[7]*LOG2E;

    const float* Bp = Bm + (size_t)b * (N_ * L_) + (size_t)(NH * g) * L_;
    const float* Cp = Cm + (size_t)b * (N_ * L_) + (size_t)(NH * g) * L_;
    const size_t chbase = (size_t)ch * L_;

    f8 carry = splat8(0.0f);

    for (int c = 0; c < NCHUNK; ++c) {
        const int off = c * LC + s * 4;

        // ---- loads: delta first (dt chain starts), then x/z, then B/C ----
        f4 dv = *(const f4*)(delta + chbase + off);
        f4 xv = *(const f4*)(x     + chbase + off);
        f4 zv = *(const f4*)(z     + chbase + off);
#define LD_BC(i) f4 Bv##i = *(const f4*)(Bp + i * L_ + off); \
                 f4 Cv##i = *(const f4*)(Cp + i * L_ + off);
        LD_BC(0) LD_BC(1) LD_BC(2) LD_BC(3) LD_BC(4) LD_BC(5) LD_BC(6) LD_BC(7)

        // ---- dt / u / dtsum ----
        float dt0 = softplus_f(dv.x + bias);
        float dt1 = softplus_f(dv.y + bias);
        float dt2 = softplus_f(dv.z + bias);
        float dt3 = softplus_f(dv.w + bias);
        float u0 = dt0 * xv.x, u1 = dt1 * xv.y, u2 = dt2 * xv.z, u3 = dt3 * xv.w;
        float dtsum = (dt0 + dt1) + (dt2 + dt3);

        // ---- per-element deltaA vectors (kept for pass 2) ----
        f8 e0 = exp2v8(splat8(dt0) * A2v);
        f8 e1 = exp2v8(splat8(dt1) * A2v);
        f8 e2 = exp2v8(splat8(dt2) * A2v);
        f8 e3 = exp2v8(splat8(dt3) * A2v);
        f8 P  = exp2v8(splat8(dtsum) * A2v);

        // ---- transpose B/C fragments to per-j state-vectors ----
        f8 tB0 = {Bv0.x,Bv1.x,Bv2.x,Bv3.x,Bv4.x,Bv5.x,Bv6.x,Bv7.x};
        f8 tB1 = {Bv0.y,Bv1.y,Bv2.y,Bv3.y,Bv4.y,Bv5.y,Bv6.y,Bv7.y};
        f8 tB2 = {Bv0.z,Bv1.z,Bv2.z,Bv3.z,Bv4.z,Bv5.z,Bv6.z,Bv7.z};
        f8 tB3 = {Bv0.w,Bv1.w,Bv2.w,Bv3.w,Bv4.w,Bv5.w,Bv6.w,Bv7.w};
        f8 uB0 = splat8(u0) * tB0;
        f8 uB1 = splat8(u1) * tB1;
        f8 uB2 = splat8(u2) * tB2;
        f8 uB3 = splat8(u3) * tB3;
        f8 SC0 = {Cv0.x,Cv1.x,Cv2.x,Cv3.x,Cv4.x,Cv5.x,Cv6.x,Cv7.x};
        f8 SC1 = {Cv0.y,Cv1.y,Cv2.y,Cv3.y,Cv4.y,Cv5.y,Cv6.y,Cv7.y};
        f8 SC2 = {Cv0.z,Cv1.z,Cv2.z,Cv3.z,Cv4.z,Cv5.z,Cv6.z,Cv7.z};
        f8 SC3 = {Cv0.w,Cv1.w,Cv2.w,Cv3.w,Cv4.w,Cv5.w,Cv6.w,Cv7.w};

        // ---- pass 1: local 4-elem scan (start h=0) ----
        f8 S = uB0;
        S = e1 * S + uB1;
        S = e2 * S + uB2;
        S = e3 * S + uB3;

        // ---- branchless width-32 inclusive scan of (P,S) ----
#pragma unroll
        for (int o = 1; o < 32; o <<= 1) {
#define SCANI(i) { float Pp = __shfl_up(P[i], o, 32); \
                   float Sp = __shfl_up(S[i], o, 32); \
                   Pp = (s >= o) ? Pp : 1.0f; \
                   Sp = (s >= o) ? Sp : 0.0f; \
                   S[i] = fmaf(Sp, P[i], S[i]); \
                   P[i] = P[i] * Pp; }
            SCANI(0) SCANI(1) SCANI(2) SCANI(3) SCANI(4) SCANI(5) SCANI(6) SCANI(7)
        }

        // ---- fold chunk carry; h entering this lane's segment ----
        f8 h;
#define CARRYI(i) { float hinc = fmaf(carry[i], P[i], S[i]); \
                    float hup  = __shfl_up(hinc, 1, 32); \
                    h[i] = (s == 0) ? carry[i] : hup; \
                    carry[i] = __shfl(hinc, 31, 32); }
        CARRYI(0) CARRYI(1) CARRYI(2) CARRYI(3) CARRYI(4) CARRYI(5) CARRYI(6) CARRYI(7)

        // ---- pass 2: recurrence (reusing e_j, uB_j); y_j = <h, C_j> ----
        h = e0 * h + uB0;  float y0 = dot8(h, SC0);
        h = e1 * h + uB1;  float y1 = dot8(h, SC1);
        h = e2 * h + uB2;  float y2 = dot8(h, SC2);
        h = e3 * h + uB3;  float y3 = dot8(h, SC3);

        // ---- combine the two state-halves; epilogue; half-wave store ----
        y0 += __shfl_xor(y0, 32, 64);
        y1 += __shfl_xor(y1, 32, 64);
        y2 += __shfl_xor(y2, 32, 64);
        y3 += __shfl_xor(y3, 32, 64);
        if (g == 0) {
            float s0 = rcpf_(1.0f + exp2f_(-zv.x * LOG2E));
            float s1 = rcpf_(1.0f + exp2f_(-zv.y * LOG2E));
            float s2 = rcpf_(1.0f + exp2f_(-zv.z * LOG2E));
            float s3 = rcpf_(1.0f + exp2f_(-zv.w * LOG2E));
            f4 ov = { (y0 + xv.x * Dd) * (zv.x * s0),
                      (y1 + xv.y * Dd) * (zv.y * s1),
                      (y2 + xv.z * Dd) * (zv.z * s2),
                      (y3 + xv.w * Dd) * (zv.w * s3) };
            *(f4*)(out + chbase + off) = ov;
        }
    }
}

extern "C" void kernel_launch(void* const* d_in, const int* in_sizes, int n_in,
                              void* d_out, int out_size, void* d_ws, size_t ws_size,
                              hipStream_t stream) {
    const float* x     = (const float*)d_in[0];
    const float* delta = (const float*)d_in[1];
    const float* A     = (const float*)d_in[2];
    const float* Bm    = (const float*)d_in[3];
    const float* Cm    = (const float*)d_in[4];
    const float* Dv    = (const float*)d_in[5];
    const float* z     = (const float*)d_in[6];
    const float* dbias = (const float*)d_in[7];
    float* out = (float*)d_out;

    dim3 grid(NCH);    // 3072 blocks = 1 wave = 1 channel each
    dim3 block(64);
    ssm_scan_kernel<<<grid, block, 0, stream>>>(x, delta, A, Bm, Cm, Dv, z, dbias, out);
}